// Round 2
// baseline (196.278 us; speedup 1.0000x reference)
//
#include <hip/hip_runtime.h>
#include <math.h>

#define IN_NODES 1152
#define OUT_NODES 10
#define IN_DIM 8
#define OUT_DIM 16
#define BATCH 256
#define CHUNKS 96
#define I_PER_CHUNK 12   // 1152 / 96
#define BTILES 8
#define BTILE 32

// ---------------------------------------------------------------------------
// xr[i, b, k] = x[b, i, k]   (one-time transpose for coalesced per-i access)
// ---------------------------------------------------------------------------
__global__ __launch_bounds__(256) void k_transpose(const float* __restrict__ x,
                                                   float* __restrict__ xr) {
    int i = blockIdx.x;   // 0..1151
    int b = threadIdx.x;  // 0..255
    const float* src = x + (size_t)b * (IN_NODES * IN_DIM) + (size_t)i * IN_DIM;
    float4 a0 = ((const float4*)src)[0];
    float4 a1 = ((const float4*)src)[1];
    float* dst = xr + (size_t)i * (BATCH * IN_DIM) + (size_t)b * IN_DIM;
    ((float4*)dst)[0] = a0;
    ((float4*)dst)[1] = a1;
}

// ---------------------------------------------------------------------------
// b_logits = 0, c = softmax(0) = 1/OUT_NODES
// ---------------------------------------------------------------------------
__global__ void k_init(float* __restrict__ blog, float* __restrict__ cbuf) {
    int t = blockIdx.x * 256 + threadIdx.x;
    if (t < IN_NODES * OUT_NODES) {
        blog[t] = 0.0f;
        cbuf[t] = 1.0f / OUT_NODES;
    }
}

// ---------------------------------------------------------------------------
// Split-K s-GEMM, LDS-free / barrier-free.
// part[chunk][j][b][d] = sum_{i in chunk} c[i,j] * (W[i,j,d,:] . x[b,i,:])
// grid = (CHUNKS, BTILES) = 768 blocks, block = 256.
// thread: d = tid&15, bq = tid>>4 -> 2 consecutive b's.
// W reads: 16 lanes share each row -> wave-broadcast, coalesced 512B/row-set.
// x reads: 1KB contiguous per (i, btile). c reads: block-uniform -> s_load.
// ---------------------------------------------------------------------------
__global__ __launch_bounds__(256) void k_s(const float* __restrict__ W,
                                           const float* __restrict__ xr,
                                           const float* __restrict__ cbuf,
                                           float* __restrict__ part) {
    const int chunk = blockIdx.x;
    const int btile = blockIdx.y;
    const int tid = threadIdx.x;
    const int d = tid & 15;
    const int bq = tid >> 4;
    const int b0 = btile * BTILE + bq * 2;

    float acc[OUT_NODES][2];
#pragma unroll
    for (int j = 0; j < OUT_NODES; ++j) { acc[j][0] = 0.f; acc[j][1] = 0.f; }

    const int i0 = chunk * I_PER_CHUNK;
#pragma unroll 2
    for (int ii = 0; ii < I_PER_CHUNK; ++ii) {
        const int i = i0 + ii;
        const float4* xp = (const float4*)(xr + ((size_t)i * BATCH + b0) * IN_DIM);
        float4 xa0 = xp[0], xa1 = xp[1];   // b0
        float4 xb0 = xp[2], xb1 = xp[3];   // b0+1
        const float* cp = cbuf + i * OUT_NODES;
        const float4* wp = (const float4*)(W + (size_t)i * 1280 + d * 8);
#pragma unroll
        for (int j = 0; j < OUT_NODES; ++j) {
            float4 w0 = wp[j * 32];
            float4 w1 = wp[j * 32 + 1];
            float c = cp[j];
            float d0 = w0.x * xa0.x;
            d0 = fmaf(w0.y, xa0.y, d0); d0 = fmaf(w0.z, xa0.z, d0);
            d0 = fmaf(w0.w, xa0.w, d0); d0 = fmaf(w1.x, xa1.x, d0);
            d0 = fmaf(w1.y, xa1.y, d0); d0 = fmaf(w1.z, xa1.z, d0);
            d0 = fmaf(w1.w, xa1.w, d0);
            float d1 = w0.x * xb0.x;
            d1 = fmaf(w0.y, xb0.y, d1); d1 = fmaf(w0.z, xb0.z, d1);
            d1 = fmaf(w0.w, xb0.w, d1); d1 = fmaf(w1.x, xb1.x, d1);
            d1 = fmaf(w1.y, xb1.y, d1); d1 = fmaf(w1.z, xb1.z, d1);
            d1 = fmaf(w1.w, xb1.w, d1);
            acc[j][0] = fmaf(c, d0, acc[j][0]);
            acc[j][1] = fmaf(c, d1, acc[j][1]);
        }
    }

    const size_t base = (size_t)chunk * OUT_NODES * BATCH * OUT_DIM;
#pragma unroll
    for (int j = 0; j < OUT_NODES; ++j) {
        part[base + ((size_t)j * BATCH + b0) * OUT_DIM + d] = acc[j][0];
        part[base + ((size_t)j * BATCH + b0 + 1) * OUT_DIM + d] = acc[j][1];
    }
}

// ---------------------------------------------------------------------------
// Reduce partials over chunks + squash.  grid = (OUT_NODES, 16), block 256.
// thread: d = tid&15, bl = tid>>4 (16 b per block). Coalesced 256B/wave loads.
// ---------------------------------------------------------------------------
__global__ __launch_bounds__(256) void k_reduce_squash(const float* __restrict__ part,
                                                       float* __restrict__ v,
                                                       float* __restrict__ out,
                                                       int write_out) {
    const int j = blockIdx.x;
    const int tid = threadIdx.x;
    const int d = tid & 15;
    const int b = blockIdx.y * 16 + (tid >> 4);

    float s = 0.f;
#pragma unroll 4
    for (int c = 0; c < CHUNKS; ++c) {
        s += part[((size_t)c * OUT_NODES + j) * (BATCH * OUT_DIM) + b * OUT_DIM + d];
    }
    float sq = s * s;
    sq += __shfl_xor(sq, 1);
    sq += __shfl_xor(sq, 2);
    sq += __shfl_xor(sq, 4);
    sq += __shfl_xor(sq, 8);
    float scale = sq / ((1.0f + sq) * sqrtf(sq));
    float vv = s * scale;
    v[((size_t)j * BATCH + b) * OUT_DIM + d] = vv;
    if (write_out) {
        out[((size_t)b * OUT_NODES + j) * OUT_DIM + d] = vv;
    }
}

// ---------------------------------------------------------------------------
// Agreement + b-logit update + softmax -> new c.  grid = IN_NODES, block = 256 (b).
// a[i,j] = (1/B) sum_b [ sum_d (W[i,j,d,:] . x[b,i,:]) * v[j,b,d] ]
// W reads block-uniform (scalar path); x 2xfloat4/thread; v coalesced 4KB/wave.
// ---------------------------------------------------------------------------
__global__ __launch_bounds__(256) void k_agree(const float* __restrict__ W,
                                               const float* __restrict__ xr,
                                               const float* __restrict__ v,
                                               float* __restrict__ blog,
                                               float* __restrict__ cbuf) {
    __shared__ float red[4][OUT_NODES];
    __shared__ float bshare[OUT_NODES];

    const int i = blockIdx.x;
    const int b = threadIdx.x;
    const int wave = b >> 6;
    const int lane = b & 63;

    const float4* xp = (const float4*)(xr + ((size_t)i * BATCH + b) * IN_DIM);
    const float4 x0 = xp[0], x1 = xp[1];

#pragma unroll 2
    for (int j = 0; j < OUT_NODES; ++j) {
        const float4* vp = (const float4*)(v + ((size_t)j * BATCH + b) * OUT_DIM);
        float4 v0 = vp[0], v1 = vp[1], v2 = vp[2], v3 = vp[3];
        float vv[16] = {v0.x, v0.y, v0.z, v0.w, v1.x, v1.y, v1.z, v1.w,
                        v2.x, v2.y, v2.z, v2.w, v3.x, v3.y, v3.z, v3.w};
        const float4* wp = (const float4*)(W + (size_t)i * 1280 + j * 128);
        float sum = 0.f;
#pragma unroll
        for (int dd = 0; dd < OUT_DIM; ++dd) {
            float4 w0 = wp[dd * 2];
            float4 w1 = wp[dd * 2 + 1];
            float u = w0.x * x0.x;
            u = fmaf(w0.y, x0.y, u); u = fmaf(w0.z, x0.z, u);
            u = fmaf(w0.w, x0.w, u); u = fmaf(w1.x, x1.x, u);
            u = fmaf(w1.y, x1.y, u); u = fmaf(w1.z, x1.z, u);
            u = fmaf(w1.w, x1.w, u);
            sum = fmaf(u, vv[dd], sum);
        }
        // reduce over 64 lanes
        sum += __shfl_xor(sum, 1);
        sum += __shfl_xor(sum, 2);
        sum += __shfl_xor(sum, 4);
        sum += __shfl_xor(sum, 8);
        sum += __shfl_xor(sum, 16);
        sum += __shfl_xor(sum, 32);
        if (lane == 0) red[wave][j] = sum;
    }
    __syncthreads();

    if (b < OUT_NODES) {
        float a = red[0][b] + red[1][b] + red[2][b] + red[3][b];
        float bn = blog[i * OUT_NODES + b] + a * (1.0f / BATCH);
        blog[i * OUT_NODES + b] = bn;
        bshare[b] = bn;
    }
    __syncthreads();

    if (b < OUT_NODES) {
        float m = bshare[0];
#pragma unroll
        for (int jj = 1; jj < OUT_NODES; ++jj) m = fmaxf(m, bshare[jj]);
        float ssum = 0.f;
#pragma unroll
        for (int jj = 0; jj < OUT_NODES; ++jj) ssum += __expf(bshare[jj] - m);
        cbuf[i * OUT_NODES + b] = __expf(bshare[b] - m) / ssum;
    }
}

// ---------------------------------------------------------------------------
extern "C" void kernel_launch(void* const* d_in, const int* in_sizes, int n_in,
                              void* d_out, int out_size, void* d_ws, size_t ws_size,
                              hipStream_t stream) {
    const float* x = (const float*)d_in[0];  // [256,1152,8]
    const float* W = (const float*)d_in[1];  // [1152,10,16,8]
    float* out = (float*)d_out;              // [256,10,16,1]
    float* ws = (float*)d_ws;

    float* xr   = ws;                                                   // 2,359,296 f
    float* part = xr + (size_t)IN_NODES * BATCH * IN_DIM;               // 3,932,160 f
    float* v    = part + (size_t)CHUNKS * OUT_NODES * BATCH * OUT_DIM;  // 40,960 f
    float* blog = v + (size_t)OUT_NODES * BATCH * OUT_DIM;              // 11,520 f
    float* cbuf = blog + (size_t)IN_NODES * OUT_NODES;                  // 11,520 f
    // total ~25.4 MB of ws

    k_transpose<<<IN_NODES, BATCH, 0, stream>>>(x, xr);
    k_init<<<(IN_NODES * OUT_NODES + 255) / 256, 256, 0, stream>>>(blog, cbuf);

    for (int it = 0; it < 3; ++it) {
        k_s<<<dim3(CHUNKS, BTILES), 256, 0, stream>>>(W, xr, cbuf, part);
        k_reduce_squash<<<dim3(OUT_NODES, 16), 256, 0, stream>>>(part, v, out,
                                                                 it == 2 ? 1 : 0);
        if (it < 2) k_agree<<<IN_NODES, 256, 0, stream>>>(W, xr, v, blog, cbuf);
    }
}

// Round 3
// 139.619 us; speedup vs baseline: 1.4058x; 1.4058x over previous
//
#include <hip/hip_runtime.h>
#include <math.h>

#define IN_NODES 1152
#define OUT_NODES 10
#define IN_DIM 8
#define OUT_DIM 16
#define BATCH 256
#define CHUNKS 128
#define I_PER_CHUNK 9    // 1152 / 128
#define M_ROWS 160       // OUT_NODES * OUT_DIM

// async global->LDS, 16B per lane
__device__ __forceinline__ void ld16(const void* g, void* l) {
    __builtin_amdgcn_global_load_lds(
        (const __attribute__((address_space(1))) unsigned int*)g,
        (__attribute__((address_space(3))) unsigned int*)l, 16, 0, 0);
}

// ---------------------------------------------------------------------------
// xr[i, b, k] = x[b, i, k]
// ---------------------------------------------------------------------------
__global__ __launch_bounds__(256) void k_transpose(const float* __restrict__ x,
                                                   float* __restrict__ xr) {
    int i = blockIdx.x;
    int b = threadIdx.x;
    const float* src = x + (size_t)b * (IN_NODES * IN_DIM) + (size_t)i * IN_DIM;
    float4 a0 = ((const float4*)src)[0];
    float4 a1 = ((const float4*)src)[1];
    float* dst = xr + (size_t)i * (BATCH * IN_DIM) + (size_t)b * IN_DIM;
    ((float4*)dst)[0] = a0;
    ((float4*)dst)[1] = a1;
}

// ---------------------------------------------------------------------------
// Wr[i][j][h][d][e] = W[i][j][d][h*4+e]   (stride 1536 floats per i, padded)
// Makes k_s LDS reads 2-way-conflict-free (16 rows x 16B contiguous per (j,h)).
// ---------------------------------------------------------------------------
__global__ __launch_bounds__(256) void k_repackW(const float* __restrict__ W,
                                                 float* __restrict__ Wr) {
    int i = blockIdx.x;
    int tid = threadIdx.x;
#pragma unroll
    for (int r = 0; r < 5; ++r) {
        int t = r * 256 + tid;          // 0..1279
        int j = t >> 7;                 // /128
        int rem = t & 127;
        int h = rem >> 6;
        int d = (rem >> 2) & 15;
        int e = rem & 3;
        Wr[(size_t)i * 1536 + j * 128 + h * 64 + d * 4 + e] =
            W[(size_t)i * 1280 + (j * 16 + d) * 8 + h * 4 + e];
    }
}

// ---------------------------------------------------------------------------
__global__ void k_init(float* __restrict__ blog, float* __restrict__ cbuf) {
    int t = blockIdx.x * 256 + threadIdx.x;
    if (t < IN_NODES * OUT_NODES) {
        blog[t] = 0.0f;
        cbuf[t] = 1.0f / OUT_NODES;
    }
}

// ---------------------------------------------------------------------------
// s-GEMM: part[chunk][b][m] = sum_{i in chunk} c[i,j] * (W[i,j,d,:] . x[b,i,:])
// grid (128, 2), 512 threads. LDS double-buffered via global_load_lds,
// counted vmcnt(2) so next-tile loads stay in flight across barriers.
// thread: dm = tid&15 (d), db = tid>>4 (0..31) -> 4 b's. 40 accumulators.
// ---------------------------------------------------------------------------
__global__ __launch_bounds__(512) void k_s(const float* __restrict__ Wr,
                                           const float* __restrict__ xr,
                                           const float* __restrict__ cbuf,
                                           float* __restrict__ part) {
    __shared__ __align__(16) float ws_[2][1536];
    __shared__ __align__(16) float xs_[2][1024];
    __shared__ float c_s[I_PER_CHUNK * OUT_NODES];

    const int chunk = blockIdx.x;
    const int btile = blockIdx.y;      // 0..1 (128 b each)
    const int tid = threadIdx.x;
    const int w = tid >> 6, lane = tid & 63;
    const int dm = tid & 15;
    const int db = tid >> 4;           // 0..31

    const int i0 = chunk * I_PER_CHUNK;
    const char* wbase = (const char*)Wr + (size_t)i0 * 6144;
    const char* xbase = (const char*)xr + (size_t)i0 * 8192 + btile * 4096;

    if (tid < I_PER_CHUNK * OUT_NODES) c_s[tid] = cbuf[chunk * (I_PER_CHUNK * OUT_NODES) + tid];

#define STAGE(BSEL, II)                                                        \
    do {                                                                       \
        const char* gw = wbase + (size_t)(II) * 6144 + w * 768 + lane * 16;    \
        char* lw = (char*)&ws_[BSEL][0] + w * 768 + lane * 16;                 \
        if (lane < 48) ld16(gw, lw);                                           \
        const char* gx = xbase + (size_t)(II) * 8192 + w * 512 + lane * 16;    \
        char* lx = (char*)&xs_[BSEL][0] + w * 512 + lane * 16;                 \
        if (lane < 32) ld16(gx, lx);                                           \
    } while (0)

    STAGE(0, 0);

    float acc[OUT_NODES][4];
#pragma unroll
    for (int j = 0; j < OUT_NODES; ++j)
#pragma unroll
        for (int bb = 0; bb < 4; ++bb) acc[j][bb] = 0.0f;

    for (int ii = 0; ii < I_PER_CHUNK; ++ii) {
        const int cur = ii & 1;
        if (ii < I_PER_CHUNK - 1) {
            STAGE(cur ^ 1, ii + 1);
            asm volatile("s_waitcnt vmcnt(2) lgkmcnt(0)\ns_barrier" ::: "memory");
        } else {
            asm volatile("s_waitcnt vmcnt(0) lgkmcnt(0)\ns_barrier" ::: "memory");
        }

        // x for this thread's 4 b's
        float xv[4][8];
#pragma unroll
        for (int bb = 0; bb < 4; ++bb) {
            float4 a0 = *(const float4*)&xs_[cur][(db * 4 + bb) * 8];
            float4 a1 = *(const float4*)&xs_[cur][(db * 4 + bb) * 8 + 4];
            xv[bb][0] = a0.x; xv[bb][1] = a0.y; xv[bb][2] = a0.z; xv[bb][3] = a0.w;
            xv[bb][4] = a1.x; xv[bb][5] = a1.y; xv[bb][6] = a1.z; xv[bb][7] = a1.w;
        }
#pragma unroll
        for (int j = 0; j < OUT_NODES; ++j) {
            float4 w0 = *(const float4*)&ws_[cur][j * 128 + dm * 4];
            float4 w1 = *(const float4*)&ws_[cur][j * 128 + 64 + dm * 4];
            float c = c_s[ii * OUT_NODES + j];
#pragma unroll
            for (int bb = 0; bb < 4; ++bb) {
                float d0 = w0.x * xv[bb][0];
                d0 = fmaf(w0.y, xv[bb][1], d0);
                d0 = fmaf(w0.z, xv[bb][2], d0);
                d0 = fmaf(w0.w, xv[bb][3], d0);
                d0 = fmaf(w1.x, xv[bb][4], d0);
                d0 = fmaf(w1.y, xv[bb][5], d0);
                d0 = fmaf(w1.z, xv[bb][6], d0);
                d0 = fmaf(w1.w, xv[bb][7], d0);
                acc[j][bb] = fmaf(c, d0, acc[j][bb]);
            }
        }
        asm volatile("s_waitcnt lgkmcnt(0)\ns_barrier" ::: "memory");
    }
#undef STAGE

    // part[chunk][b][m], m = j*16+dm
#pragma unroll
    for (int j = 0; j < OUT_NODES; ++j)
#pragma unroll
        for (int bb = 0; bb < 4; ++bb) {
            int b = btile * 128 + db * 4 + bb;
            part[((size_t)chunk * BATCH + b) * M_ROWS + j * 16 + dm] = acc[j][bb];
        }
}

// ---------------------------------------------------------------------------
// Reduce over chunks + squash. grid 256 (one b each), 192 threads (160 active).
// ---------------------------------------------------------------------------
__global__ __launch_bounds__(192) void k_reduce_squash(const float* __restrict__ part,
                                                       float* __restrict__ v,
                                                       float* __restrict__ out,
                                                       int write_out) {
    const int b = blockIdx.x;
    const int tid = threadIdx.x;
    if (tid >= M_ROWS) return;
    const int j = tid >> 4;
    const int d = tid & 15;

    float s = 0.f;
#pragma unroll 8
    for (int c = 0; c < CHUNKS; ++c)
        s += part[((size_t)c * BATCH + b) * M_ROWS + tid];

    float sq = s * s;
    sq += __shfl_xor(sq, 1);
    sq += __shfl_xor(sq, 2);
    sq += __shfl_xor(sq, 4);
    sq += __shfl_xor(sq, 8);
    float scale = sq / ((1.0f + sq) * sqrtf(sq));
    float vv = s * scale;
    v[((size_t)j * BATCH + b) * OUT_DIM + d] = vv;
    if (write_out) out[((size_t)b * OUT_NODES + j) * OUT_DIM + d] = vv;
}

// ---------------------------------------------------------------------------
// Agreement + b-logit update + softmax. grid 1152, 256 threads (b-parallel).
// W[i] staged in LDS (uniform-address broadcast reads), 4 rotating partials.
// ---------------------------------------------------------------------------
__global__ __launch_bounds__(256) void k_agree(const float* __restrict__ W,
                                               const float* __restrict__ xr,
                                               const float* __restrict__ v,
                                               float* __restrict__ blog,
                                               float* __restrict__ cbuf) {
    __shared__ __align__(16) float W_s[1280];
    __shared__ float red[4][OUT_NODES];
    __shared__ float bsh[OUT_NODES];

    const int i = blockIdx.x;
    const int tid = threadIdx.x;
    const int w = tid >> 6, lane = tid & 63;

    {
        const char* gw = (const char*)W + (size_t)i * 5120 + w * 1280 + lane * 16;
        char* lw = (char*)&W_s[0] + w * 1280 + lane * 16;
        ld16(gw, lw);
        if (lane < 16) ld16(gw + 1024, lw + 1024);
    }
    asm volatile("s_waitcnt vmcnt(0)" ::: "memory");
    __syncthreads();

    const int b = tid;
    const float4* xp = (const float4*)(xr + ((size_t)i * BATCH + b) * IN_DIM);
    const float4 x0 = xp[0], x1 = xp[1];

#pragma unroll 2
    for (int j = 0; j < OUT_NODES; ++j) {
        const float4* vp = (const float4*)(v + ((size_t)j * BATCH + b) * OUT_DIM);
        float4 v0 = vp[0], v1 = vp[1], v2 = vp[2], v3 = vp[3];
        float vv[16] = {v0.x, v0.y, v0.z, v0.w, v1.x, v1.y, v1.z, v1.w,
                        v2.x, v2.y, v2.z, v2.w, v3.x, v3.y, v3.z, v3.w};
        float s0 = 0.f, s1 = 0.f, s2 = 0.f, s3 = 0.f;
#pragma unroll
        for (int d = 0; d < OUT_DIM; ++d) {
            float4 w0 = *(const float4*)&W_s[(j * 16 + d) * 8];
            float4 w1 = *(const float4*)&W_s[(j * 16 + d) * 8 + 4];
            float u = w0.x * x0.x;
            u = fmaf(w0.y, x0.y, u); u = fmaf(w0.z, x0.z, u);
            u = fmaf(w0.w, x0.w, u); u = fmaf(w1.x, x1.x, u);
            u = fmaf(w1.y, x1.y, u); u = fmaf(w1.z, x1.z, u);
            u = fmaf(w1.w, x1.w, u);
            if ((d & 3) == 0) s0 = fmaf(u, vv[d], s0);
            else if ((d & 3) == 1) s1 = fmaf(u, vv[d], s1);
            else if ((d & 3) == 2) s2 = fmaf(u, vv[d], s2);
            else s3 = fmaf(u, vv[d], s3);
        }
        float sum = (s0 + s1) + (s2 + s3);
        sum += __shfl_xor(sum, 1);
        sum += __shfl_xor(sum, 2);
        sum += __shfl_xor(sum, 4);
        sum += __shfl_xor(sum, 8);
        sum += __shfl_xor(sum, 16);
        sum += __shfl_xor(sum, 32);
        if (lane == 0) red[w][j] = sum;
    }
    __syncthreads();

    if (tid < OUT_NODES) {
        float a = red[0][tid] + red[1][tid] + red[2][tid] + red[3][tid];
        float bn = blog[i * OUT_NODES + tid] + a * (1.0f / BATCH);
        blog[i * OUT_NODES + tid] = bn;
        bsh[tid] = bn;
    }
    __syncthreads();

    if (tid < OUT_NODES) {
        float m = bsh[0];
#pragma unroll
        for (int jj = 1; jj < OUT_NODES; ++jj) m = fmaxf(m, bsh[jj]);
        float ssum = 0.f;
#pragma unroll
        for (int jj = 0; jj < OUT_NODES; ++jj) ssum += __expf(bsh[jj] - m);
        cbuf[i * OUT_NODES + tid] = __expf(bsh[tid] - m) / ssum;
    }
}

// ---------------------------------------------------------------------------
extern "C" void kernel_launch(void* const* d_in, const int* in_sizes, int n_in,
                              void* d_out, int out_size, void* d_ws, size_t ws_size,
                              hipStream_t stream) {
    const float* x = (const float*)d_in[0];  // [256,1152,8]
    const float* W = (const float*)d_in[1];  // [1152,10,16,8]
    float* out = (float*)d_out;              // [256,10,16,1]
    float* ws = (float*)d_ws;

    float* xr   = ws;                                                  // 2,359,296 f
    float* Wr   = xr + (size_t)IN_NODES * BATCH * IN_DIM;              // 1,769,472 f
    float* part = Wr + (size_t)IN_NODES * 1536;                        // 5,242,880 f
    float* v    = part + (size_t)CHUNKS * BATCH * M_ROWS;              // 40,960 f
    float* blog = v + (size_t)OUT_NODES * BATCH * OUT_DIM;             // 11,520 f
    float* cbuf = blog + (size_t)IN_NODES * OUT_NODES;                 // 11,520 f
    // total ~37.7 MB of ws

    k_transpose<<<IN_NODES, BATCH, 0, stream>>>(x, xr);
    k_repackW<<<IN_NODES, 256, 0, stream>>>(W, Wr);
    k_init<<<(IN_NODES * OUT_NODES + 255) / 256, 256, 0, stream>>>(blog, cbuf);

    for (int it = 0; it < 3; ++it) {
        k_s<<<dim3(CHUNKS, 2), 512, 0, stream>>>(Wr, xr, cbuf, part);
        k_reduce_squash<<<BATCH, 192, 0, stream>>>(part, v, out, it == 2 ? 1 : 0);
        if (it < 2) k_agree<<<IN_NODES, 256, 0, stream>>>(W, xr, v, blog, cbuf);
    }
}

// Round 4
// 129.129 us; speedup vs baseline: 1.5200x; 1.0812x over previous
//
#include <hip/hip_runtime.h>
#include <math.h>

#define IN_NODES 1152
#define OUT_NODES 10
#define IN_DIM 8
#define OUT_DIM 16
#define BATCH 256
#define CHUNKS 128
#define I_PER_CHUNK 9    // 1152 / 128
#define M_ROWS 160       // OUT_NODES * OUT_DIM

// async global->LDS, 16B per lane
__device__ __forceinline__ void ld16(const void* g, void* l) {
    __builtin_amdgcn_global_load_lds(
        (const __attribute__((address_space(1))) unsigned int*)g,
        (__attribute__((address_space(3))) unsigned int*)l, 16, 0, 0);
}

// ---------------------------------------------------------------------------
// Fused prep: xr[i,b,k] = x[b,i,k]; Wr = repacked W; blog=0; cbuf=0.1
// Wr[i][j][h][d][e] = W[i][j][d][h*4+e]  (stride 1536 floats per i)
// ---------------------------------------------------------------------------
__global__ __launch_bounds__(256) void k_prep(const float* __restrict__ x,
                                              const float* __restrict__ W,
                                              float* __restrict__ xr,
                                              float* __restrict__ Wr,
                                              float* __restrict__ blog,
                                              float* __restrict__ cbuf) {
    const int i = blockIdx.x;
    const int tid = threadIdx.x;

    const float* src = x + (size_t)tid * (IN_NODES * IN_DIM) + (size_t)i * IN_DIM;
    float4 a0 = ((const float4*)src)[0];
    float4 a1 = ((const float4*)src)[1];
    float* dst = xr + (size_t)i * (BATCH * IN_DIM) + (size_t)tid * IN_DIM;
    ((float4*)dst)[0] = a0;
    ((float4*)dst)[1] = a1;

#pragma unroll
    for (int r = 0; r < 5; ++r) {
        int t = r * 256 + tid;          // 0..1279
        int j = t >> 7;
        int rem = t & 127;
        int h = rem >> 6;
        int d = (rem >> 2) & 15;
        int e = rem & 3;
        Wr[(size_t)i * 1536 + j * 128 + h * 64 + d * 4 + e] =
            W[(size_t)i * 1280 + (j * 16 + d) * 8 + h * 4 + e];
    }

    if (tid < OUT_NODES) {
        blog[i * OUT_NODES + tid] = 0.0f;
        cbuf[i * OUT_NODES + tid] = 1.0f / OUT_NODES;
    }
}

// ---------------------------------------------------------------------------
// s-GEMM: part[chunk][b][m] = sum_{i in chunk} c[i,j] * (W[i,j,d,:] . x[b,i,:])
// grid (128, 4) = 512 blocks (2 blocks/CU), 256 threads (4 waves).
// Double-buffered LDS via global_load_lds, counted vmcnt(2).
// thread: dm = tid&15 (d), db = tid>>4 (0..15) -> 4 b's. 40 accumulators.
// ---------------------------------------------------------------------------
__global__ __launch_bounds__(256) void k_s(const float* __restrict__ Wr,
                                           const float* __restrict__ xr,
                                           const float* __restrict__ cbuf,
                                           float* __restrict__ part) {
    __shared__ __align__(16) float ws_[2][1536];
    __shared__ __align__(16) float xs_[2][512];
    __shared__ float c_s[I_PER_CHUNK * OUT_NODES];

    const int chunk = blockIdx.x;
    const int btile = blockIdx.y;      // 0..3 (64 b each)
    const int tid = threadIdx.x;
    const int dm = tid & 15;
    const int db = tid >> 4;           // 0..15

    const int i0 = chunk * I_PER_CHUNK;
    const char* wbase = (const char*)Wr + (size_t)i0 * 6144;
    const char* xbase = (const char*)xr + (size_t)i0 * 8192 + btile * 2048;

    if (tid < I_PER_CHUNK * OUT_NODES)
        c_s[tid] = cbuf[chunk * (I_PER_CHUNK * OUT_NODES) + tid];

    // W tile: 1536 floats = 384 16B-slots; x tile: 512 floats = 128 slots.
    // op1: all 256 threads -> W slots 0..255
    // op2: tid<128 -> W slots 256..383 (waves 0,1); tid>=128 -> x slots 0..127 (waves 2,3)
#define STAGE(BSEL, II)                                                          \
    do {                                                                         \
        const char* gw = wbase + (size_t)(II) * 6144;                            \
        char* lw = (char*)&ws_[BSEL][0];                                         \
        ld16(gw + tid * 16, lw + tid * 16);                                      \
        if (tid < 128) {                                                         \
            ld16(gw + 4096 + tid * 16, lw + 4096 + tid * 16);                    \
        } else {                                                                 \
            ld16(xbase + (size_t)(II) * 8192 + (tid - 128) * 16,                 \
                 (char*)&xs_[BSEL][0] + (tid - 128) * 16);                       \
        }                                                                        \
    } while (0)

    STAGE(0, 0);

    float acc[OUT_NODES][4];
#pragma unroll
    for (int j = 0; j < OUT_NODES; ++j)
#pragma unroll
        for (int bb = 0; bb < 4; ++bb) acc[j][bb] = 0.0f;

    for (int ii = 0; ii < I_PER_CHUNK; ++ii) {
        const int cur = ii & 1;
        if (ii < I_PER_CHUNK - 1) {
            STAGE(cur ^ 1, ii + 1);
            asm volatile("s_waitcnt vmcnt(2) lgkmcnt(0)\ns_barrier" ::: "memory");
        } else {
            asm volatile("s_waitcnt vmcnt(0) lgkmcnt(0)\ns_barrier" ::: "memory");
        }

        float xv[4][8];
#pragma unroll
        for (int bb = 0; bb < 4; ++bb) {
            float4 a0 = *(const float4*)&xs_[cur][(db * 4 + bb) * 8];
            float4 a1 = *(const float4*)&xs_[cur][(db * 4 + bb) * 8 + 4];
            xv[bb][0] = a0.x; xv[bb][1] = a0.y; xv[bb][2] = a0.z; xv[bb][3] = a0.w;
            xv[bb][4] = a1.x; xv[bb][5] = a1.y; xv[bb][6] = a1.z; xv[bb][7] = a1.w;
        }
#pragma unroll
        for (int j = 0; j < OUT_NODES; ++j) {
            float4 w0 = *(const float4*)&ws_[cur][j * 128 + dm * 4];
            float4 w1 = *(const float4*)&ws_[cur][j * 128 + 64 + dm * 4];
            float c = c_s[ii * OUT_NODES + j];
#pragma unroll
            for (int bb = 0; bb < 4; ++bb) {
                float d0 = w0.x * xv[bb][0];
                d0 = fmaf(w0.y, xv[bb][1], d0);
                d0 = fmaf(w0.z, xv[bb][2], d0);
                d0 = fmaf(w0.w, xv[bb][3], d0);
                d0 = fmaf(w1.x, xv[bb][4], d0);
                d0 = fmaf(w1.y, xv[bb][5], d0);
                d0 = fmaf(w1.z, xv[bb][6], d0);
                d0 = fmaf(w1.w, xv[bb][7], d0);
                acc[j][bb] = fmaf(c, d0, acc[j][bb]);
            }
        }
        asm volatile("s_waitcnt lgkmcnt(0)\ns_barrier" ::: "memory");
    }
#undef STAGE

#pragma unroll
    for (int j = 0; j < OUT_NODES; ++j)
#pragma unroll
        for (int bb = 0; bb < 4; ++bb) {
            int b = btile * 64 + db * 4 + bb;
            part[((size_t)chunk * BATCH + b) * M_ROWS + j * 16 + dm] = acc[j][bb];
        }
}

// ---------------------------------------------------------------------------
// Reduce over chunks + squash. grid 256 (one b each), 192 threads (160 active).
// ---------------------------------------------------------------------------
__global__ __launch_bounds__(192) void k_reduce_squash(const float* __restrict__ part,
                                                       float* __restrict__ v,
                                                       float* __restrict__ out,
                                                       int write_out) {
    const int b = blockIdx.x;
    const int tid = threadIdx.x;
    if (tid >= M_ROWS) return;
    const int j = tid >> 4;
    const int d = tid & 15;

    float s = 0.f;
#pragma unroll 8
    for (int c = 0; c < CHUNKS; ++c)
        s += part[((size_t)c * BATCH + b) * M_ROWS + tid];

    float sq = s * s;
    sq += __shfl_xor(sq, 1);
    sq += __shfl_xor(sq, 2);
    sq += __shfl_xor(sq, 4);
    sq += __shfl_xor(sq, 8);
    float scale = sq / ((1.0f + sq) * sqrtf(sq));
    float vv = s * scale;
    v[((size_t)j * BATCH + b) * OUT_DIM + d] = vv;
    if (write_out) out[((size_t)b * OUT_NODES + j) * OUT_DIM + d] = vv;
}

// ---------------------------------------------------------------------------
// Agreement + b-logit update + softmax. grid 1152, 256 threads (b-parallel).
// ---------------------------------------------------------------------------
__global__ __launch_bounds__(256) void k_agree(const float* __restrict__ W,
                                               const float* __restrict__ xr,
                                               const float* __restrict__ v,
                                               float* __restrict__ blog,
                                               float* __restrict__ cbuf) {
    __shared__ __align__(16) float W_s[1280];
    __shared__ float red[4][OUT_NODES];
    __shared__ float bsh[OUT_NODES];

    const int i = blockIdx.x;
    const int tid = threadIdx.x;
    const int w = tid >> 6, lane = tid & 63;

    {
        const char* gw = (const char*)W + (size_t)i * 5120 + w * 1280 + lane * 16;
        char* lw = (char*)&W_s[0] + w * 1280 + lane * 16;
        ld16(gw, lw);
        if (lane < 16) ld16(gw + 1024, lw + 1024);
    }
    asm volatile("s_waitcnt vmcnt(0)" ::: "memory");
    __syncthreads();

    const int b = tid;
    const float4* xp = (const float4*)(xr + ((size_t)i * BATCH + b) * IN_DIM);
    const float4 x0 = xp[0], x1 = xp[1];

#pragma unroll 2
    for (int j = 0; j < OUT_NODES; ++j) {
        const float4* vp = (const float4*)(v + ((size_t)j * BATCH + b) * OUT_DIM);
        float4 v0 = vp[0], v1 = vp[1], v2 = vp[2], v3 = vp[3];
        float vv[16] = {v0.x, v0.y, v0.z, v0.w, v1.x, v1.y, v1.z, v1.w,
                        v2.x, v2.y, v2.z, v2.w, v3.x, v3.y, v3.z, v3.w};
        float s0 = 0.f, s1 = 0.f, s2 = 0.f, s3 = 0.f;
#pragma unroll
        for (int d = 0; d < OUT_DIM; ++d) {
            float4 w0 = *(const float4*)&W_s[(j * 16 + d) * 8];
            float4 w1 = *(const float4*)&W_s[(j * 16 + d) * 8 + 4];
            float u = w0.x * x0.x;
            u = fmaf(w0.y, x0.y, u); u = fmaf(w0.z, x0.z, u);
            u = fmaf(w0.w, x0.w, u); u = fmaf(w1.x, x1.x, u);
            u = fmaf(w1.y, x1.y, u); u = fmaf(w1.z, x1.z, u);
            u = fmaf(w1.w, x1.w, u);
            if ((d & 3) == 0) s0 = fmaf(u, vv[d], s0);
            else if ((d & 3) == 1) s1 = fmaf(u, vv[d], s1);
            else if ((d & 3) == 2) s2 = fmaf(u, vv[d], s2);
            else s3 = fmaf(u, vv[d], s3);
        }
        float sum = (s0 + s1) + (s2 + s3);
        sum += __shfl_xor(sum, 1);
        sum += __shfl_xor(sum, 2);
        sum += __shfl_xor(sum, 4);
        sum += __shfl_xor(sum, 8);
        sum += __shfl_xor(sum, 16);
        sum += __shfl_xor(sum, 32);
        if (lane == 0) red[w][j] = sum;
    }
    __syncthreads();

    if (tid < OUT_NODES) {
        float a = red[0][tid] + red[1][tid] + red[2][tid] + red[3][tid];
        float bn = blog[i * OUT_NODES + tid] + a * (1.0f / BATCH);
        blog[i * OUT_NODES + tid] = bn;
        bsh[tid] = bn;
    }
    __syncthreads();

    if (tid < OUT_NODES) {
        float m = bsh[0];
#pragma unroll
        for (int jj = 1; jj < OUT_NODES; ++jj) m = fmaxf(m, bsh[jj]);
        float ssum = 0.f;
#pragma unroll
        for (int jj = 0; jj < OUT_NODES; ++jj) ssum += __expf(bsh[jj] - m);
        cbuf[i * OUT_NODES + tid] = __expf(bsh[tid] - m) / ssum;
    }
}

// ---------------------------------------------------------------------------
extern "C" void kernel_launch(void* const* d_in, const int* in_sizes, int n_in,
                              void* d_out, int out_size, void* d_ws, size_t ws_size,
                              hipStream_t stream) {
    const float* x = (const float*)d_in[0];  // [256,1152,8]
    const float* W = (const float*)d_in[1];  // [1152,10,16,8]
    float* out = (float*)d_out;              // [256,10,16,1]
    float* ws = (float*)d_ws;

    float* xr   = ws;                                                  // 2,359,296 f
    float* Wr   = xr + (size_t)IN_NODES * BATCH * IN_DIM;              // 1,769,472 f
    float* part = Wr + (size_t)IN_NODES * 1536;                        // 5,242,880 f
    float* v    = part + (size_t)CHUNKS * BATCH * M_ROWS;              // 40,960 f
    float* blog = v + (size_t)OUT_NODES * BATCH * OUT_DIM;             // 11,520 f
    float* cbuf = blog + (size_t)IN_NODES * OUT_NODES;                 // 11,520 f

    k_prep<<<IN_NODES, 256, 0, stream>>>(x, W, xr, Wr, blog, cbuf);

    for (int it = 0; it < 3; ++it) {
        k_s<<<dim3(CHUNKS, 4), 256, 0, stream>>>(Wr, xr, cbuf, part);
        k_reduce_squash<<<BATCH, 192, 0, stream>>>(part, v, out, it == 2 ? 1 : 0);
        if (it < 2) k_agree<<<IN_NODES, 256, 0, stream>>>(W, xr, v, blog, cbuf);
    }
}